// Round 1
// baseline (2710.356 us; speedup 1.0000x reference)
//
#include <hip/hip_runtime.h>
#include <cstdint>
#include <cmath>

#define GG 128
#define SS 2048
#define LL 256
#define FF 512
#define DD 512

// ---------------------------------------------------------------------------
// Generic tiled fp32 GEMM: C[M,N] = A[M,K] @ B[K,N] (+ bias[N] if non-null)
// BM=64, BN=64, BK=16, 256 threads, 4x4 accumulators per thread.
// Requires M%64==0, N%64==0, K%16==0 (all shapes here satisfy this).
// ---------------------------------------------------------------------------
__global__ __launch_bounds__(256) void gemm_bias_kernel(
    const float* __restrict__ A, const float* __restrict__ B,
    const float* __restrict__ bias, float* __restrict__ C,
    int M, int N, int K) {
  __shared__ float As[16][65];   // [k][m], padded to dodge write conflicts
  __shared__ float Bs[16][64];   // [k][n]
  const int t  = threadIdx.x;
  const int tx = t & 15;         // n-direction
  const int ty = t >> 4;         // m-direction
  const int row0 = blockIdx.y * 64;
  const int col0 = blockIdx.x * 64;

  float acc[4][4] = {{0.f}};

  for (int k0 = 0; k0 < K; k0 += 16) {
    // load A tile (64 rows x 16 k), store k-major
    for (int i = t; i < 64 * 16; i += 256) {
      int r = i >> 4, c = i & 15;
      As[c][r] = A[(size_t)(row0 + r) * K + (k0 + c)];
    }
    // load B tile (16 k x 64 cols)
    for (int i = t; i < 16 * 64; i += 256) {
      int r = i >> 6, c = i & 63;
      Bs[r][c] = B[(size_t)(k0 + r) * N + (col0 + c)];
    }
    __syncthreads();
#pragma unroll
    for (int k = 0; k < 16; ++k) {
      const float4 b = *(const float4*)&Bs[k][tx * 4];
      float a[4];
#pragma unroll
      for (int i = 0; i < 4; ++i) a[i] = As[k][ty * 4 + i];
#pragma unroll
      for (int i = 0; i < 4; ++i) {
        acc[i][0] += a[i] * b.x;
        acc[i][1] += a[i] * b.y;
        acc[i][2] += a[i] * b.z;
        acc[i][3] += a[i] * b.w;
      }
    }
    __syncthreads();
  }

  float4 bv = make_float4(0.f, 0.f, 0.f, 0.f);
  if (bias) bv = *(const float4*)&bias[col0 + tx * 4];
#pragma unroll
  for (int i = 0; i < 4; ++i) {
    float4 v;
    v.x = acc[i][0] + bv.x;
    v.y = acc[i][1] + bv.y;
    v.z = acc[i][2] + bv.z;
    v.w = acc[i][3] + bv.w;
    *(float4*)&C[(size_t)(row0 + ty * 4 + i) * N + (col0 + tx * 4)] = v;
  }
}

// ---------------------------------------------------------------------------
// Attention: one block per (query row l, group g). 256 threads.
// scores[l,m] = Q[l]·K[m] (m < n), softmax over m, ctx[l] = attn @ V.
// ---------------------------------------------------------------------------
__global__ __launch_bounds__(256) void attn_kernel(
    const float* __restrict__ Q, const float* __restrict__ K,
    const float* __restrict__ V, const int* __restrict__ lengths,
    float* __restrict__ ctx) {
  const int l = blockIdx.x;
  const int g = blockIdx.y;
  const int t = threadIdx.x;
  const int n = lengths[g];

  __shared__ float q[DD];
  __shared__ float attn[LL];
  __shared__ float red[8];

  const float* Qrow = Q + ((size_t)g * LL + l) * DD;
  for (int i = t; i < DD; i += 256) q[i] = Qrow[i];
  __syncthreads();

  // score for key row t
  float s = -INFINITY;
  if (t < n) {
    const float* Krow = K + ((size_t)g * LL + t) * DD;
    float acc = 0.f;
#pragma unroll 4
    for (int k = 0; k < DD; k += 4) {
      const float4 kv = *(const float4*)(Krow + k);
      acc += q[k] * kv.x + q[k + 1] * kv.y + q[k + 2] * kv.z + q[k + 3] * kv.w;
    }
    s = acc;
  }

  const int wave = t >> 6, lane = t & 63;
  // block max
  float m = s;
  for (int off = 32; off > 0; off >>= 1) m = fmaxf(m, __shfl_down(m, off));
  if (lane == 0) red[wave] = m;
  __syncthreads();
  const float mglob = fmaxf(fmaxf(red[0], red[1]), fmaxf(red[2], red[3]));

  float e = (t < n) ? expf(s - mglob) : 0.f;
  // block sum
  float sum = e;
  for (int off = 32; off > 0; off >>= 1) sum += __shfl_down(sum, off);
  __syncthreads();
  if (lane == 0) red[wave] = sum;
  __syncthreads();
  const float denom = red[0] + red[1] + red[2] + red[3];

  attn[t] = e / denom;
  __syncthreads();

  float* crow = ctx + ((size_t)g * LL + l) * DD;
  for (int d = t; d < DD; d += 256) {
    float acc = 0.f;
    for (int mi = 0; mi < n; ++mi)
      acc += attn[mi] * V[((size_t)g * LL + mi) * DD + d];
    crow[d] = acc;
  }
}

// ---------------------------------------------------------------------------
// Final MLP layer (D64 -> 1) fused with length==1 onehot + key-mask zeroing.
// ---------------------------------------------------------------------------
__global__ __launch_bounds__(256) void score_kernel(
    const float* __restrict__ h3, const float* __restrict__ W4,
    const float* __restrict__ b4, const int* __restrict__ lengths,
    float* __restrict__ w) {
  __shared__ float w4[64];
  const int t = threadIdx.x;
  if (t < 64) w4[t] = W4[t];
  __syncthreads();
  const int idx = blockIdx.x * 256 + t;
  const int g = idx >> 8, l = idx & 255;
  const int n = lengths[g];
  float val;
  if (n == 1) {
    val = (l == 0) ? 1.f : 0.f;
  } else if (l >= n) {
    val = 0.f;
  } else {
    const float* row = h3 + (size_t)idx * 64;
    float acc = b4[0];
#pragma unroll
    for (int k = 0; k < 64; ++k) acc += row[k] * w4[k];
    val = acc;
  }
  w[idx] = val;
}

// ---------------------------------------------------------------------------
// out[s,g] = sum_l raw[g,s,l] * w[g,l].  One wave per sample row.
// ---------------------------------------------------------------------------
__global__ __launch_bounds__(256) void out_kernel(
    const float* __restrict__ raw, const float* __restrict__ w,
    float* __restrict__ out) {
  __shared__ float wl[LL];
  const int g = blockIdx.x;
  const int t = threadIdx.x;
  wl[t] = w[g * LL + t];
  __syncthreads();
  const int wave = t >> 6, lane = t & 63;
  const int s = blockIdx.y * 4 + wave;
  const float* rp = raw + ((size_t)g * SS + s) * LL;
  float acc = 0.f;
#pragma unroll
  for (int c = 0; c < 4; ++c) acc += rp[c * 64 + lane] * wl[c * 64 + lane];
  for (int off = 32; off > 0; off >>= 1) acc += __shfl_down(acc, off);
  if (lane == 0) out[(size_t)s * GG + g] = acc;
}

// ---------------------------------------------------------------------------
extern "C" void kernel_launch(void* const* d_in, const int* in_sizes, int n_in,
                              void* d_out, int out_size, void* d_ws, size_t ws_size,
                              hipStream_t stream) {
  const float* raw  = (const float*)d_in[0];
  const float* info = (const float*)d_in[1];
  const float* Wq   = (const float*)d_in[2];
  const float* Wk   = (const float*)d_in[3];
  const float* Wv   = (const float*)d_in[4];
  const float* W1   = (const float*)d_in[5];
  const float* b1   = (const float*)d_in[6];
  const float* W2   = (const float*)d_in[7];
  const float* b2   = (const float*)d_in[8];
  const float* W3   = (const float*)d_in[9];
  const float* b3   = (const float*)d_in[10];
  const float* W4   = (const float*)d_in[11];
  const float* b4   = (const float*)d_in[12];
  const int* lengths = (const int*)d_in[13];
  float* out = (float*)d_out;

  float* ws = (float*)d_ws;
  const size_t QN = (size_t)GG * LL * DD;  // 16,777,216 floats
  float* Q   = ws;
  float* Kb  = ws + QN;
  float* Vb  = ws + 2 * QN;
  float* ctx = ws + 3 * QN;
  float* h1  = Q;    // reuse: Q dead after attention
  float* h2  = Kb;
  float* h3  = Vb;
  float* w   = ws + 4 * QN;  // 32768 floats

  const int M = GG * LL;  // 32768
  dim3 blk(256);

  // QKV projections: [M,512] @ [512,512]
  gemm_bias_kernel<<<dim3(DD / 64, M / 64), blk, 0, stream>>>(info, Wq, nullptr, Q,  M, DD, FF);
  gemm_bias_kernel<<<dim3(DD / 64, M / 64), blk, 0, stream>>>(info, Wk, nullptr, Kb, M, DD, FF);
  gemm_bias_kernel<<<dim3(DD / 64, M / 64), blk, 0, stream>>>(info, Wv, nullptr, Vb, M, DD, FF);

  // attention per (l, g)
  attn_kernel<<<dim3(LL, GG), blk, 0, stream>>>(Q, Kb, Vb, lengths, ctx);

  // MLP
  gemm_bias_kernel<<<dim3(256 / 64, M / 64), blk, 0, stream>>>(ctx, W1, b1, h1, M, 256, DD);
  gemm_bias_kernel<<<dim3(128 / 64, M / 64), blk, 0, stream>>>(h1,  W2, b2, h2, M, 128, 256);
  gemm_bias_kernel<<<dim3(64  / 64, M / 64), blk, 0, stream>>>(h2,  W3, b3, h3, M, 64,  128);

  // final layer + onehot/mask semantics
  score_kernel<<<dim3(M / 256), blk, 0, stream>>>(h3, W4, b4, lengths, w);

  // out[s,g] = raw[g,s,:] · w[g,:]
  out_kernel<<<dim3(GG, SS / 4), blk, 0, stream>>>(raw, w, out);
}

// Round 3
// 508.209 us; speedup vs baseline: 5.3332x; 5.3332x over previous
//
#include <hip/hip_runtime.h>
#include <hip/hip_bf16.h>
#include <cstdint>
#include <cmath>

#define GG 128
#define SS 2048
#define LL 256
#define FF 512
#define DD 512

typedef __bf16 bf16_t;
typedef __bf16 bf16x8 __attribute__((ext_vector_type(8)));
typedef __bf16 bf16x4 __attribute__((ext_vector_type(4)));
typedef float  f32x4  __attribute__((ext_vector_type(4)));

#define MiB (1024UL * 1024UL)
// ---------------- workspace layout (peak ~261 MiB) ----------------
#define OFF_INFO_HI (0 * MiB)                  // [32768][512] bf16; later S fp32 [32768][256]
#define OFF_INFO_LO (32 * MiB)                 // [32768][512] bf16; later ctx bf16 [32768][512]
#define OFF_Q_HI    (64 * MiB)                 // [32768][512] bf16; later P bf16 [32768][256]
#define OFF_Q_LO    (96 * MiB)                 // [32768][512] bf16; later h1 bf16 [32768][256]
#define OFF_K_HI    (128 * MiB)
#define OFF_K_LO    (160 * MiB)
#define OFF_V       (192 * MiB)                // [32768][512] bf16
#define OFF_VT      (224 * MiB)                // [128][512][256] bf16
#define OFF_WQT_HI  (256 * MiB)
#define OFF_WQT_LO  (256 * MiB + 512 * 1024)
#define OFF_WKT_HI  (257 * MiB)
#define OFF_WKT_LO  (257 * MiB + 512 * 1024)
#define OFF_WVT     (258 * MiB)
#define OFF_W1T     (258 * MiB + 512 * 1024)
#define OFF_W2T     (259 * MiB)
#define OFF_W3T     (259 * MiB + 128 * 1024)
#define OFF_WVEC    (260 * MiB)                // w fp32 [32768]
#define OFF_S       OFF_INFO_HI
#define OFF_CTX     OFF_INFO_LO
#define OFF_P       OFF_Q_HI
#define OFF_H1      OFF_Q_LO
#define OFF_H2      (112 * MiB)
#define OFF_H3      (120 * MiB)

// ---------------------------------------------------------------------------
// fp32 -> (hi, lo) bf16 split cast
// ---------------------------------------------------------------------------
__global__ __launch_bounds__(256) void cast_split_kernel(
    const float* __restrict__ in, bf16_t* __restrict__ hi,
    bf16_t* __restrict__ lo, int n4) {
  int i = blockIdx.x * 256 + threadIdx.x;
  if (i >= n4) return;
  float4 v = *(const float4*)&in[(size_t)i * 4];
  float x[4] = {v.x, v.y, v.z, v.w};
  bf16x4 h, l;
#pragma unroll
  for (int e = 0; e < 4; ++e) {
    h[e] = (bf16_t)x[e];
    l[e] = (bf16_t)(x[e] - (float)h[e]);
  }
  *(bf16x4*)&hi[(size_t)i * 4] = h;
  *(bf16x4*)&lo[(size_t)i * 4] = l;
}

// transposed split cast for weights: dst[c][r] = split(src[r][c])
__global__ __launch_bounds__(256) void transpose_cast_split_kernel(
    const float* __restrict__ src, bf16_t* __restrict__ hi,
    bf16_t* __restrict__ lo, int R, int C) {
  int i = blockIdx.x * 256 + threadIdx.x;
  if (i >= R * C) return;
  int r = i / C, c = i % C;
  float x = src[i];
  bf16_t h = (bf16_t)x;
  hi[(size_t)c * R + r] = h;
  if (lo) lo[(size_t)c * R + r] = (bf16_t)(x - (float)h);
}

// ---------------------------------------------------------------------------
// gemm_bt: C[b] = Ahi[b] @ Bhi[b]^T (+ Ahi@Blo^T + Alo@Bhi^T if split)
// BM=128, BK=64, 256 threads (4 waves 2x2), XOR-swizzled LDS, MFMA 16x16x32.
// OUTMODE: 0 = fp32, 1 = bf16, 2 = split bf16 (hi->C0, lo->C1)
// ---------------------------------------------------------------------------
template <int BN, bool ASPLIT, bool BSPLIT, int OUTMODE, bool BIAS>
__global__ __launch_bounds__(256) void gemm_bt(
    const bf16_t* __restrict__ Ahi, const bf16_t* __restrict__ Alo, int lda, long sA,
    const bf16_t* __restrict__ Bhi, const bf16_t* __restrict__ Blo, int ldb, long sB,
    void* __restrict__ C0, void* __restrict__ C1, int ldc, long sC,
    const float* __restrict__ bias, int K) {
  constexpr int BM = 128;
  constexpr int BK = 64;
  constexpr int WM = 4;
  constexpr int WN = BN / 32;
  constexpr int PA = BM * BK;
  constexpr int PB = BN * BK;
  __shared__ bf16_t As[(ASPLIT ? 2 : 1) * PA];
  __shared__ bf16_t Bs[(BSPLIT ? 2 : 1) * PB];

  const int t = threadIdx.x;
  const int lane = t & 63;
  const int wave = t >> 6;
  const int wm = (wave >> 1) * 64;
  const int wn = (wave & 1) * (BN / 2);
  const int m0 = blockIdx.y * BM;
  const int n0 = blockIdx.x * BN;
  const int b  = blockIdx.z;

  const bf16_t* Ah = Ahi + (size_t)b * sA;
  const bf16_t* Al = ASPLIT ? Alo + (size_t)b * sA : nullptr;
  const bf16_t* Bh = Bhi + (size_t)b * sB;
  const bf16_t* Bl = BSPLIT ? Blo + (size_t)b * sB : nullptr;

  f32x4 acc[WM][WN];
#pragma unroll
  for (int i = 0; i < WM; ++i)
#pragma unroll
    for (int j = 0; j < WN; ++j) acc[i][j] = {0.f, 0.f, 0.f, 0.f};

  const int fr = lane & 15;
  const int fs = lane >> 4;

  for (int k0 = 0; k0 < K; k0 += BK) {
    for (int c = t; c < BM * 8; c += 256) {
      int r = c >> 3, s = c & 7;
      size_t ga = (size_t)(m0 + r) * lda + k0 + s * 8;
      int la = r * BK + ((s ^ (r & 7)) * 8);
      *(bf16x8*)&As[la] = *(const bf16x8*)&Ah[ga];
      if (ASPLIT) *(bf16x8*)&As[PA + la] = *(const bf16x8*)&Al[ga];
    }
    for (int c = t; c < BN * 8; c += 256) {
      int r = c >> 3, s = c & 7;
      size_t ga = (size_t)(n0 + r) * ldb + k0 + s * 8;
      int la = r * BK + ((s ^ (r & 7)) * 8);
      *(bf16x8*)&Bs[la] = *(const bf16x8*)&Bh[ga];
      if (BSPLIT) *(bf16x8*)&Bs[PB + la] = *(const bf16x8*)&Bl[ga];
    }
    __syncthreads();
#pragma unroll
    for (int kk = 0; kk < 2; ++kk) {
      bf16x8 ah[WM], al[WM], bh[WN], bl[WN];
#pragma unroll
      for (int i = 0; i < WM; ++i) {
        int r = wm + i * 16 + fr;
        int la = r * BK + (((kk * 4 + fs) ^ (r & 7)) * 8);
        ah[i] = *(const bf16x8*)&As[la];
        if (ASPLIT) al[i] = *(const bf16x8*)&As[PA + la];
      }
#pragma unroll
      for (int j = 0; j < WN; ++j) {
        int r = wn + j * 16 + fr;
        int la = r * BK + (((kk * 4 + fs) ^ (r & 7)) * 8);
        bh[j] = *(const bf16x8*)&Bs[la];
        if (BSPLIT) bl[j] = *(const bf16x8*)&Bs[PB + la];
      }
#pragma unroll
      for (int i = 0; i < WM; ++i)
#pragma unroll
        for (int j = 0; j < WN; ++j) {
          acc[i][j] = __builtin_amdgcn_mfma_f32_16x16x32_bf16(ah[i], bh[j], acc[i][j], 0, 0, 0);
          if (BSPLIT)
            acc[i][j] = __builtin_amdgcn_mfma_f32_16x16x32_bf16(ah[i], bl[j], acc[i][j], 0, 0, 0);
          if (ASPLIT)
            acc[i][j] = __builtin_amdgcn_mfma_f32_16x16x32_bf16(al[i], bh[j], acc[i][j], 0, 0, 0);
        }
    }
    __syncthreads();
  }

#pragma unroll
  for (int i = 0; i < WM; ++i) {
#pragma unroll
    for (int j = 0; j < WN; ++j) {
      const int col = n0 + wn + j * 16 + fr;
      float bv = 0.f;
      if (BIAS) bv = bias[col];
#pragma unroll
      for (int jj = 0; jj < 4; ++jj) {
        const int row = m0 + wm + i * 16 + fs * 4 + jj;
        const float v = acc[i][j][jj] + bv;
        const size_t off = (size_t)b * sC + (size_t)row * ldc + col;
        if (OUTMODE == 0) {
          ((float*)C0)[off] = v;
        } else if (OUTMODE == 1) {
          ((bf16_t*)C0)[off] = (bf16_t)v;
        } else {
          bf16_t h = (bf16_t)v;
          ((bf16_t*)C0)[off] = h;
          ((bf16_t*)C1)[off] = (bf16_t)(v - (float)h);
        }
      }
    }
  }
}

// ---------------------------------------------------------------------------
// V transpose: Vt[g][d][m] = V[(g*256+m)][d]
// ---------------------------------------------------------------------------
__global__ __launch_bounds__(256) void transpose_v_kernel(
    const bf16_t* __restrict__ V, bf16_t* __restrict__ Vt) {
  __shared__ bf16_t tile[64][65];
  const int g = blockIdx.z;
  const int m0 = blockIdx.y * 64;
  const int d0 = blockIdx.x * 64;
  const int t = threadIdx.x;
  for (int i = t; i < 64 * 8; i += 256) {
    int r = i >> 3, c = i & 7;
    bf16x8 v = *(const bf16x8*)&V[((size_t)g * 256 + m0 + r) * 512 + d0 + c * 8];
#pragma unroll
    for (int e = 0; e < 8; ++e) tile[r][c * 8 + e] = v[e];
  }
  __syncthreads();
  for (int i = t; i < 64 * 8; i += 256) {
    int r = i >> 3, c = i & 7;
    bf16x8 v;
#pragma unroll
    for (int e = 0; e < 8; ++e) v[e] = tile[c * 8 + e][r];
    *(bf16x8*)&Vt[((size_t)g * 512 + d0 + r) * 256 + m0 + c * 8] = v;
  }
}

// ---------------------------------------------------------------------------
// masked softmax: S fp32 -> P bf16, one wave per row
// ---------------------------------------------------------------------------
__global__ __launch_bounds__(256) void softmax_kernel(
    const float* __restrict__ S, bf16_t* __restrict__ P,
    const int* __restrict__ lengths) {
  const int t = threadIdx.x, lane = t & 63, wave = t >> 6;
  const int row = blockIdx.x * 4 + wave;
  const int g = row >> 8;
  const int n = lengths[g];
  const float* srow = S + (size_t)row * 256;
  const int c0 = lane * 4;
  float4 v = *(const float4*)&srow[c0];
  float s[4] = {v.x, v.y, v.z, v.w};
  float m = -INFINITY;
#pragma unroll
  for (int e = 0; e < 4; ++e)
    if (c0 + e < n) m = fmaxf(m, s[e]);
#pragma unroll
  for (int off = 32; off > 0; off >>= 1) m = fmaxf(m, __shfl_xor(m, off));
  float e4[4];
  float sum = 0.f;
#pragma unroll
  for (int e = 0; e < 4; ++e) {
    e4[e] = (c0 + e < n) ? __expf(s[e] - m) : 0.f;
    sum += e4[e];
  }
#pragma unroll
  for (int off = 32; off > 0; off >>= 1) sum += __shfl_xor(sum, off);
  const float inv = 1.f / sum;
  bf16x4 p;
#pragma unroll
  for (int e = 0; e < 4; ++e) p[e] = (bf16_t)(e4[e] * inv);
  *(bf16x4*)&P[(size_t)row * 256 + c0] = p;
}

// ---------------------------------------------------------------------------
// final scorer + length==1 onehot + key-mask zeroing
// ---------------------------------------------------------------------------
__global__ __launch_bounds__(256) void score_kernel(
    const bf16_t* __restrict__ h3, const float* __restrict__ W4,
    const float* __restrict__ b4, const int* __restrict__ lengths,
    float* __restrict__ w) {
  __shared__ float w4[64];
  const int t = threadIdx.x;
  if (t < 64) w4[t] = W4[t];
  __syncthreads();
  const int idx = blockIdx.x * 256 + t;
  const int g = idx >> 8, l = idx & 255;
  const int n = lengths[g];
  float val;
  if (n == 1) {
    val = (l == 0) ? 1.f : 0.f;
  } else if (l >= n) {
    val = 0.f;
  } else {
    const bf16_t* row = h3 + (size_t)idx * 64;
    float acc = b4[0];
#pragma unroll
    for (int k = 0; k < 64; ++k) acc += (float)row[k] * w4[k];
    val = acc;
  }
  w[idx] = val;
}

// ---------------------------------------------------------------------------
// out[s,g] = sum_l raw[g,s,l] * w[g,l]
// ---------------------------------------------------------------------------
__global__ __launch_bounds__(256) void out_kernel(
    const float* __restrict__ raw, const float* __restrict__ w,
    float* __restrict__ out) {
  __shared__ float wl[LL];
  const int g = blockIdx.x;
  const int t = threadIdx.x;
  wl[t] = w[g * LL + t];
  __syncthreads();
  const int wave = t >> 6, lane = t & 63;
  const int s = blockIdx.y * 4 + wave;
  const float* rp = raw + ((size_t)g * SS + s) * LL;
  float acc = 0.f;
#pragma unroll
  for (int c = 0; c < 4; ++c) acc += rp[c * 64 + lane] * wl[c * 64 + lane];
  for (int off = 32; off > 0; off >>= 1) acc += __shfl_down(acc, off);
  if (lane == 0) out[(size_t)s * GG + g] = acc;
}

// ---------------------------------------------------------------------------
extern "C" void kernel_launch(void* const* d_in, const int* in_sizes, int n_in,
                              void* d_out, int out_size, void* d_ws, size_t ws_size,
                              hipStream_t stream) {
  const float* raw  = (const float*)d_in[0];
  const float* info = (const float*)d_in[1];
  const float* Wq   = (const float*)d_in[2];
  const float* Wk   = (const float*)d_in[3];
  const float* Wv   = (const float*)d_in[4];
  const float* W1   = (const float*)d_in[5];
  const float* b1   = (const float*)d_in[6];
  const float* W2   = (const float*)d_in[7];
  const float* b2   = (const float*)d_in[8];
  const float* W3   = (const float*)d_in[9];
  const float* b3   = (const float*)d_in[10];
  const float* W4   = (const float*)d_in[11];
  const float* b4   = (const float*)d_in[12];
  const int* lengths = (const int*)d_in[13];
  float* out = (float*)d_out;

  char* ws = (char*)d_ws;
  bf16_t* info_hi = (bf16_t*)(ws + OFF_INFO_HI);
  bf16_t* info_lo = (bf16_t*)(ws + OFF_INFO_LO);
  bf16_t* Qhi = (bf16_t*)(ws + OFF_Q_HI);
  bf16_t* Qlo = (bf16_t*)(ws + OFF_Q_LO);
  bf16_t* Khi = (bf16_t*)(ws + OFF_K_HI);
  bf16_t* Klo = (bf16_t*)(ws + OFF_K_LO);
  bf16_t* V   = (bf16_t*)(ws + OFF_V);
  bf16_t* Vt  = (bf16_t*)(ws + OFF_VT);
  bf16_t* Wqt_hi = (bf16_t*)(ws + OFF_WQT_HI);
  bf16_t* Wqt_lo = (bf16_t*)(ws + OFF_WQT_LO);
  bf16_t* Wkt_hi = (bf16_t*)(ws + OFF_WKT_HI);
  bf16_t* Wkt_lo = (bf16_t*)(ws + OFF_WKT_LO);
  bf16_t* Wvt = (bf16_t*)(ws + OFF_WVT);
  bf16_t* W1t = (bf16_t*)(ws + OFF_W1T);
  bf16_t* W2t = (bf16_t*)(ws + OFF_W2T);
  bf16_t* W3t = (bf16_t*)(ws + OFF_W3T);
  float*  S   = (float*)(ws + OFF_S);
  bf16_t* ctx = (bf16_t*)(ws + OFF_CTX);
  bf16_t* P   = (bf16_t*)(ws + OFF_P);
  bf16_t* h1  = (bf16_t*)(ws + OFF_H1);
  bf16_t* h2  = (bf16_t*)(ws + OFF_H2);
  bf16_t* h3  = (bf16_t*)(ws + OFF_H3);
  float*  w   = (float*)(ws + OFF_WVEC);

  dim3 blk(256);
  const int M = GG * LL;  // 32768

  // input + weight preparation
  cast_split_kernel<<<dim3(M * FF / 4 / 256), blk, 0, stream>>>(info, info_hi, info_lo, M * FF / 4);
  transpose_cast_split_kernel<<<dim3(FF * DD / 256), blk, 0, stream>>>(Wq, Wqt_hi, Wqt_lo, FF, DD);
  transpose_cast_split_kernel<<<dim3(FF * DD / 256), blk, 0, stream>>>(Wk, Wkt_hi, Wkt_lo, FF, DD);
  transpose_cast_split_kernel<<<dim3(FF * DD / 256), blk, 0, stream>>>(Wv, Wvt, nullptr, FF, DD);
  transpose_cast_split_kernel<<<dim3(512 * 256 / 256), blk, 0, stream>>>(W1, W1t, nullptr, 512, 256);
  transpose_cast_split_kernel<<<dim3(256 * 128 / 256), blk, 0, stream>>>(W2, W2t, nullptr, 256, 128);
  transpose_cast_split_kernel<<<dim3(128 * 64 / 256),  blk, 0, stream>>>(W3, W3t, nullptr, 128, 64);

  // Q, K: split x split -> split out (precision-critical for argmax-like softmax)
  gemm_bt<128, true, true, 2, false><<<dim3(4, M / 128, 1), blk, 0, stream>>>(
      info_hi, info_lo, 512, 0, Wqt_hi, Wqt_lo, 512, 0, Qhi, Qlo, 512, 0, nullptr, 512);
  gemm_bt<128, true, true, 2, false><<<dim3(4, M / 128, 1), blk, 0, stream>>>(
      info_hi, info_lo, 512, 0, Wkt_hi, Wkt_lo, 512, 0, Khi, Klo, 512, 0, nullptr, 512);
  // V: plain bf16
  gemm_bt<128, false, false, 1, false><<<dim3(4, M / 128, 1), blk, 0, stream>>>(
      info_hi, nullptr, 512, 0, Wvt, nullptr, 512, 0, V, nullptr, 512, 0, nullptr, 512);

  transpose_v_kernel<<<dim3(8, 4, GG), blk, 0, stream>>>(V, Vt);

  // S[g] = Q[g] @ K[g]^T, 3-term split -> fp32 (overlays dead info_hi)
  gemm_bt<128, true, true, 0, false><<<dim3(2, 2, GG), blk, 0, stream>>>(
      Qhi, Qlo, 512, 256L * 512, Khi, Klo, 512, 256L * 512,
      S, nullptr, 256, 256L * 256, nullptr, 512);

  softmax_kernel<<<dim3(M / 4), blk, 0, stream>>>(S, P, lengths);

  // ctx[g] = P[g] @ V[g]
  gemm_bt<128, false, false, 1, false><<<dim3(4, 2, GG), blk, 0, stream>>>(
      P, nullptr, 256, 256L * 256, Vt, nullptr, 256, 512L * 256,
      ctx, nullptr, 512, 256L * 512, nullptr, 256);

  // MLP
  gemm_bt<128, false, false, 1, true><<<dim3(2, M / 128, 1), blk, 0, stream>>>(
      ctx, nullptr, 512, 0, W1t, nullptr, 512, 0, h1, nullptr, 256, 0, b1, 512);
  gemm_bt<128, false, false, 1, true><<<dim3(1, M / 128, 1), blk, 0, stream>>>(
      h1, nullptr, 256, 0, W2t, nullptr, 256, 0, h2, nullptr, 128, 0, b2, 256);
  gemm_bt<64, false, false, 1, true><<<dim3(1, M / 128, 1), blk, 0, stream>>>(
      h2, nullptr, 128, 0, W3t, nullptr, 128, 0, h3, nullptr, 64, 0, b3, 128);

  score_kernel<<<dim3(M / 256), blk, 0, stream>>>(h3, W4, b4, lengths, w);
  out_kernel<<<dim3(GG, SS / 4), blk, 0, stream>>>(raw, w, out);
}

// Round 4
// 435.665 us; speedup vs baseline: 6.2212x; 1.1665x over previous
//
#include <hip/hip_runtime.h>
#include <hip/hip_bf16.h>
#include <cstdint>
#include <cmath>

#define GG 128
#define SS 2048
#define LL 256
#define FF 512
#define DD 512

typedef __bf16 bf16_t;
typedef __bf16 bf16x8 __attribute__((ext_vector_type(8)));
typedef __bf16 bf16x4 __attribute__((ext_vector_type(4)));
typedef float  f32x4  __attribute__((ext_vector_type(4)));

#define MiB (1024UL * 1024UL)
// ---------------- workspace layout (~198 MiB peak) ----------------
#define OFF_INFO_HI (0 * MiB)     // bf16 [32768][512]; later ctx bf16 [32768][512]
#define OFF_INFO_LO (32 * MiB)    // bf16 [32768][512]; later h1/h2/h3
#define OFF_T_HI    (64 * MiB)    // bf16 [32768][512]; later P bf16 [32768][256]
#define OFF_T_LO    (96 * MiB)
#define OFF_V       (128 * MiB)   // bf16 [32768][512]; later S fp32 [32768][256]
#define OFF_VT      (160 * MiB)   // bf16 [128][512][256]
#define OFF_WQ_HI   (192 * MiB)
#define OFF_WQ_LO   (192 * MiB + 512 * 1024)
#define OFF_WK_HI   (193 * MiB)
#define OFF_WK_LO   (193 * MiB + 512 * 1024)
#define OFF_GT_HI   (194 * MiB)
#define OFF_GT_LO   (194 * MiB + 512 * 1024)
#define OFF_WVT     (195 * MiB)
#define OFF_W1T     (195 * MiB + 512 * 1024)
#define OFF_W2T     (196 * MiB)
#define OFF_W3T     (196 * MiB + 128 * 1024)
#define OFF_WVEC    (197 * MiB)
// overlays
#define OFF_CTX     OFF_INFO_HI
#define OFF_H1      OFF_INFO_LO            // bf16 [32768][256] (16 MiB)
#define OFF_H2      (OFF_INFO_LO + 16 * MiB)
#define OFF_H3      (OFF_INFO_LO + 24 * MiB)
#define OFF_P       OFF_T_HI               // bf16 [32768][256]
#define OFF_S       OFF_V                  // fp32 [32768][256] (32 MiB)

// ---------------------------------------------------------------------------
// fp32 -> (hi, lo) bf16 split cast
// ---------------------------------------------------------------------------
__global__ __launch_bounds__(256) void cast_split_kernel(
    const float* __restrict__ in, bf16_t* __restrict__ hi,
    bf16_t* __restrict__ lo, int n4) {
  int i = blockIdx.x * 256 + threadIdx.x;
  if (i >= n4) return;
  float4 v = *(const float4*)&in[(size_t)i * 4];
  float x[4] = {v.x, v.y, v.z, v.w};
  bf16x4 h, l;
#pragma unroll
  for (int e = 0; e < 4; ++e) {
    h[e] = (bf16_t)x[e];
    l[e] = (bf16_t)(x[e] - (float)h[e]);
  }
  *(bf16x4*)&hi[(size_t)i * 4] = h;
  *(bf16x4*)&lo[(size_t)i * 4] = l;
}

// transposed cast: dst[c][r] = bf16(src[r][c])
__global__ __launch_bounds__(256) void transpose_cast_kernel(
    const float* __restrict__ src, bf16_t* __restrict__ dst, int R, int C) {
  int i = blockIdx.x * 256 + threadIdx.x;
  if (i >= R * C) return;
  int r = i / C, c = i % C;
  dst[(size_t)c * R + r] = (bf16_t)src[i];
}

// ---------------------------------------------------------------------------
// gemm_bt: C[b] = A[b] @ Bt[b]^T (+bias). Split-bf16 3-term when A/BSPLIT.
// BM=128, BK=64, 256 threads (4 waves 2x2), XOR-swizzled LDS, MFMA 16x16x32.
// OUTMODE: 0 = fp32, 1 = bf16, 2 = split bf16 (hi->C0, lo->C1)
// SKIP: 0 none; 1 global-M rows (g=m0>>8, skip if (m0&255)>=n);
//       2 batched rows (g=z, skip m0>=n); 3 batched rows+cols (also n0>=n)
// ---------------------------------------------------------------------------
template <int BN, bool ASPLIT, bool BSPLIT, int OUTMODE, bool BIAS, int SKIP>
__global__ __launch_bounds__(256) void gemm_bt(
    const bf16_t* __restrict__ Ahi, const bf16_t* __restrict__ Alo, int lda, long sA,
    const bf16_t* __restrict__ Bhi, const bf16_t* __restrict__ Blo, int ldb, long sB,
    void* __restrict__ C0, void* __restrict__ C1, int ldc, long sC,
    const float* __restrict__ bias, int K, const int* __restrict__ lengths) {
  constexpr int BM = 128;
  constexpr int BK = 64;
  constexpr int WM = 4;
  constexpr int WN = BN / 32;
  constexpr int PA = BM * BK;
  constexpr int PB = BN * BK;
  __shared__ bf16_t As[(ASPLIT ? 2 : 1) * PA];
  __shared__ bf16_t Bs[(BSPLIT ? 2 : 1) * PB];

  const int m0 = blockIdx.y * BM;
  const int n0 = blockIdx.x * BN;
  const int b  = blockIdx.z;

  if (SKIP == 1) { if ((m0 & 255) >= lengths[m0 >> 8]) return; }
  if (SKIP == 2) { if (m0 >= lengths[b]) return; }
  if (SKIP == 3) { int n = lengths[b]; if (m0 >= n || n0 >= n) return; }

  const int t = threadIdx.x;
  const int lane = t & 63;
  const int wave = t >> 6;
  const int wm = (wave >> 1) * 64;
  const int wn = (wave & 1) * (BN / 2);

  const bf16_t* Ah = Ahi + (size_t)b * sA;
  const bf16_t* Al = ASPLIT ? Alo + (size_t)b * sA : nullptr;
  const bf16_t* Bh = Bhi + (size_t)b * sB;
  const bf16_t* Bl = BSPLIT ? Blo + (size_t)b * sB : nullptr;

  f32x4 acc[WM][WN];
#pragma unroll
  for (int i = 0; i < WM; ++i)
#pragma unroll
    for (int j = 0; j < WN; ++j) acc[i][j] = {0.f, 0.f, 0.f, 0.f};

  const int fr = lane & 15;
  const int fs = lane >> 4;

  for (int k0 = 0; k0 < K; k0 += BK) {
    for (int c = t; c < BM * 8; c += 256) {
      int r = c >> 3, s = c & 7;
      size_t ga = (size_t)(m0 + r) * lda + k0 + s * 8;
      int la = r * BK + ((s ^ (r & 7)) * 8);
      *(bf16x8*)&As[la] = *(const bf16x8*)&Ah[ga];
      if (ASPLIT) *(bf16x8*)&As[PA + la] = *(const bf16x8*)&Al[ga];
    }
    for (int c = t; c < BN * 8; c += 256) {
      int r = c >> 3, s = c & 7;
      size_t ga = (size_t)(n0 + r) * ldb + k0 + s * 8;
      int la = r * BK + ((s ^ (r & 7)) * 8);
      *(bf16x8*)&Bs[la] = *(const bf16x8*)&Bh[ga];
      if (BSPLIT) *(bf16x8*)&Bs[PB + la] = *(const bf16x8*)&Bl[ga];
    }
    __syncthreads();
#pragma unroll
    for (int kk = 0; kk < 2; ++kk) {
      bf16x8 ah[WM], al[WM], bh[WN], bl[WN];
#pragma unroll
      for (int i = 0; i < WM; ++i) {
        int r = wm + i * 16 + fr;
        int la = r * BK + (((kk * 4 + fs) ^ (r & 7)) * 8);
        ah[i] = *(const bf16x8*)&As[la];
        if (ASPLIT) al[i] = *(const bf16x8*)&As[PA + la];
      }
#pragma unroll
      for (int j = 0; j < WN; ++j) {
        int r = wn + j * 16 + fr;
        int la = r * BK + (((kk * 4 + fs) ^ (r & 7)) * 8);
        bh[j] = *(const bf16x8*)&Bs[la];
        if (BSPLIT) bl[j] = *(const bf16x8*)&Bs[PB + la];
      }
#pragma unroll
      for (int i = 0; i < WM; ++i)
#pragma unroll
        for (int j = 0; j < WN; ++j) {
          acc[i][j] = __builtin_amdgcn_mfma_f32_16x16x32_bf16(ah[i], bh[j], acc[i][j], 0, 0, 0);
          if (BSPLIT)
            acc[i][j] = __builtin_amdgcn_mfma_f32_16x16x32_bf16(ah[i], bl[j], acc[i][j], 0, 0, 0);
          if (ASPLIT)
            acc[i][j] = __builtin_amdgcn_mfma_f32_16x16x32_bf16(al[i], bh[j], acc[i][j], 0, 0, 0);
        }
    }
    __syncthreads();
  }

#pragma unroll
  for (int i = 0; i < WM; ++i) {
#pragma unroll
    for (int j = 0; j < WN; ++j) {
      const int col = n0 + wn + j * 16 + fr;
      float bv = 0.f;
      if (BIAS) bv = bias[col];
#pragma unroll
      for (int jj = 0; jj < 4; ++jj) {
        const int row = m0 + wm + i * 16 + fs * 4 + jj;
        const float v = acc[i][j][jj] + bv;
        const size_t off = (size_t)b * sC + (size_t)row * ldc + col;
        if (OUTMODE == 0) {
          ((float*)C0)[off] = v;
        } else if (OUTMODE == 1) {
          ((bf16_t*)C0)[off] = (bf16_t)v;
        } else {
          bf16_t h = (bf16_t)v;
          ((bf16_t*)C0)[off] = h;
          ((bf16_t*)C1)[off] = (bf16_t)(v - (float)h);
        }
      }
    }
  }
}

// ---------------------------------------------------------------------------
// V transpose: Vt[g][d][m] = V[(g*256+m)][d]
// ---------------------------------------------------------------------------
__global__ __launch_bounds__(256) void transpose_v_kernel(
    const bf16_t* __restrict__ V, bf16_t* __restrict__ Vt) {
  __shared__ bf16_t tile[64][65];
  const int g = blockIdx.z;
  const int m0 = blockIdx.y * 64;
  const int d0 = blockIdx.x * 64;
  const int t = threadIdx.x;
  for (int i = t; i < 64 * 8; i += 256) {
    int r = i >> 3, c = i & 7;
    bf16x8 v = *(const bf16x8*)&V[((size_t)g * 256 + m0 + r) * 512 + d0 + c * 8];
#pragma unroll
    for (int e = 0; e < 8; ++e) tile[r][c * 8 + e] = v[e];
  }
  __syncthreads();
  for (int i = t; i < 64 * 8; i += 256) {
    int r = i >> 3, c = i & 7;
    bf16x8 v;
#pragma unroll
    for (int e = 0; e < 8; ++e) v[e] = tile[c * 8 + e][r];
    *(bf16x8*)&Vt[((size_t)g * 512 + d0 + r) * 256 + m0 + c * 8] = v;
  }
}

// ---------------------------------------------------------------------------
// masked softmax: S fp32 -> P bf16, one wave per row; invalid rows skipped
// ---------------------------------------------------------------------------
__global__ __launch_bounds__(256) void softmax_kernel(
    const float* __restrict__ S, bf16_t* __restrict__ P,
    const int* __restrict__ lengths) {
  const int t = threadIdx.x, lane = t & 63, wave = t >> 6;
  const int row = blockIdx.x * 4 + wave;
  const int g = row >> 8;
  const int n = lengths[g];
  if ((row & 255) >= n) return;  // invalid query row: P never read downstream
  const float* srow = S + (size_t)row * 256;
  const int c0 = lane * 4;
  float4 v = *(const float4*)&srow[c0];
  float s[4] = {v.x, v.y, v.z, v.w};
  float m = -INFINITY;
#pragma unroll
  for (int e = 0; e < 4; ++e)
    if (c0 + e < n) m = fmaxf(m, s[e]);
#pragma unroll
  for (int off = 32; off > 0; off >>= 1) m = fmaxf(m, __shfl_xor(m, off));
  float e4[4];
  float sum = 0.f;
#pragma unroll
  for (int e = 0; e < 4; ++e) {
    e4[e] = (c0 + e < n) ? __expf(s[e] - m) : 0.f;
    sum += e4[e];
  }
#pragma unroll
  for (int off = 32; off > 0; off >>= 1) sum += __shfl_xor(sum, off);
  const float inv = 1.f / sum;
  bf16x4 p;
#pragma unroll
  for (int e = 0; e < 4; ++e) p[e] = (bf16_t)(e4[e] * inv);
  *(bf16x4*)&P[(size_t)row * 256 + c0] = p;
}

// ---------------------------------------------------------------------------
// final scorer + length==1 onehot + key-mask zeroing
// ---------------------------------------------------------------------------
__global__ __launch_bounds__(256) void score_kernel(
    const bf16_t* __restrict__ h3, const float* __restrict__ W4,
    const float* __restrict__ b4, const int* __restrict__ lengths,
    float* __restrict__ w) {
  __shared__ float w4[64];
  const int t = threadIdx.x;
  if (t < 64) w4[t] = W4[t];
  __syncthreads();
  const int idx = blockIdx.x * 256 + t;
  const int g = idx >> 8, l = idx & 255;
  const int n = lengths[g];
  float val;
  if (n == 1) {
    val = (l == 0) ? 1.f : 0.f;
  } else if (l >= n) {
    val = 0.f;
  } else {
    const bf16_t* row = h3 + (size_t)idx * 64;
    float acc = b4[0];
#pragma unroll
    for (int k = 0; k < 64; ++k) acc += (float)row[k] * w4[k];
    val = acc;
  }
  w[idx] = val;
}

// ---------------------------------------------------------------------------
// out[s,g] = sum_l raw[g,s,l] * w[g,l]
// ---------------------------------------------------------------------------
__global__ __launch_bounds__(256) void out_kernel(
    const float* __restrict__ raw, const float* __restrict__ w,
    float* __restrict__ out) {
  __shared__ float wl[LL];
  const int g = blockIdx.x;
  const int t = threadIdx.x;
  wl[t] = w[g * LL + t];
  __syncthreads();
  const int wave = t >> 6, lane = t & 63;
  const int s = blockIdx.y * 4 + wave;
  const float* rp = raw + ((size_t)g * SS + s) * LL;
  float acc = 0.f;
#pragma unroll
  for (int c = 0; c < 4; ++c) acc += rp[c * 64 + lane] * wl[c * 64 + lane];
  for (int off = 32; off > 0; off >>= 1) acc += __shfl_down(acc, off);
  if (lane == 0) out[(size_t)s * GG + g] = acc;
}

// ---------------------------------------------------------------------------
extern "C" void kernel_launch(void* const* d_in, const int* in_sizes, int n_in,
                              void* d_out, int out_size, void* d_ws, size_t ws_size,
                              hipStream_t stream) {
  const float* raw  = (const float*)d_in[0];
  const float* info = (const float*)d_in[1];
  const float* Wq   = (const float*)d_in[2];
  const float* Wk   = (const float*)d_in[3];
  const float* Wv   = (const float*)d_in[4];
  const float* W1   = (const float*)d_in[5];
  const float* b1   = (const float*)d_in[6];
  const float* W2   = (const float*)d_in[7];
  const float* b2   = (const float*)d_in[8];
  const float* W3   = (const float*)d_in[9];
  const float* b3   = (const float*)d_in[10];
  const float* W4   = (const float*)d_in[11];
  const float* b4   = (const float*)d_in[12];
  const int* lengths = (const int*)d_in[13];
  float* out = (float*)d_out;

  char* ws = (char*)d_ws;
  bf16_t* info_hi = (bf16_t*)(ws + OFF_INFO_HI);
  bf16_t* info_lo = (bf16_t*)(ws + OFF_INFO_LO);
  bf16_t* T_hi = (bf16_t*)(ws + OFF_T_HI);
  bf16_t* T_lo = (bf16_t*)(ws + OFF_T_LO);
  bf16_t* V    = (bf16_t*)(ws + OFF_V);
  bf16_t* Vt   = (bf16_t*)(ws + OFF_VT);
  bf16_t* Wq_hi = (bf16_t*)(ws + OFF_WQ_HI);
  bf16_t* Wq_lo = (bf16_t*)(ws + OFF_WQ_LO);
  bf16_t* Wk_hi = (bf16_t*)(ws + OFF_WK_HI);
  bf16_t* Wk_lo = (bf16_t*)(ws + OFF_WK_LO);
  bf16_t* Gt_hi = (bf16_t*)(ws + OFF_GT_HI);
  bf16_t* Gt_lo = (bf16_t*)(ws + OFF_GT_LO);
  bf16_t* Wvt = (bf16_t*)(ws + OFF_WVT);
  bf16_t* W1t = (bf16_t*)(ws + OFF_W1T);
  bf16_t* W2t = (bf16_t*)(ws + OFF_W2T);
  bf16_t* W3t = (bf16_t*)(ws + OFF_W3T);
  float*  S   = (float*)(ws + OFF_S);
  bf16_t* ctx = (bf16_t*)(ws + OFF_CTX);
  bf16_t* P   = (bf16_t*)(ws + OFF_P);
  bf16_t* h1  = (bf16_t*)(ws + OFF_H1);
  bf16_t* h2  = (bf16_t*)(ws + OFF_H2);
  bf16_t* h3  = (bf16_t*)(ws + OFF_H3);
  float*  w   = (float*)(ws + OFF_WVEC);

  dim3 blk(256);
  const int M = GG * LL;  // 32768

  // preparation
  cast_split_kernel<<<dim3(M * FF / 4 / 256), blk, 0, stream>>>(info, info_hi, info_lo, M * FF / 4);
  cast_split_kernel<<<dim3(FF * DD / 4 / 256), blk, 0, stream>>>(Wq, Wq_hi, Wq_lo, FF * DD / 4);
  cast_split_kernel<<<dim3(FF * DD / 4 / 256), blk, 0, stream>>>(Wk, Wk_hi, Wk_lo, FF * DD / 4);
  transpose_cast_kernel<<<dim3(FF * DD / 256), blk, 0, stream>>>(Wv, Wvt, FF, DD);
  transpose_cast_kernel<<<dim3(512 * 256 / 256), blk, 0, stream>>>(W1, W1t, 512, 256);
  transpose_cast_kernel<<<dim3(256 * 128 / 256), blk, 0, stream>>>(W2, W2t, 256, 128);
  transpose_cast_kernel<<<dim3(128 * 64 / 256),  blk, 0, stream>>>(W3, W3t, 128, 64);

  // Gt = Wk @ Wq^T (split): Gt^T = Wq @ Wk^T = G
  gemm_bt<128, true, true, 2, false, 0><<<dim3(4, 4, 1), blk, 0, stream>>>(
      Wk_hi, Wk_lo, 512, 0, Wq_hi, Wq_lo, 512, 0, Gt_hi, Gt_lo, 512, 0, nullptr, 512, nullptr);

  // T = info @ G (split out), skip fully-masked row blocks
  gemm_bt<128, true, true, 2, false, 1><<<dim3(4, M / 128, 1), blk, 0, stream>>>(
      info_hi, info_lo, 512, 0, Gt_hi, Gt_lo, 512, 0, T_hi, T_lo, 512, 0, nullptr, 512, lengths);

  // V = info @ Wv (plain bf16), skip fully-masked row blocks
  gemm_bt<128, false, false, 1, false, 1><<<dim3(4, M / 128, 1), blk, 0, stream>>>(
      info_hi, nullptr, 512, 0, Wvt, nullptr, 512, 0, V, nullptr, 512, 0, nullptr, 512, lengths);

  transpose_v_kernel<<<dim3(8, 4, GG), blk, 0, stream>>>(V, Vt);

  // S[g] = T[g] @ info[g]^T (3-term split -> fp32), skip masked row/col tiles
  gemm_bt<128, true, true, 0, false, 3><<<dim3(2, 2, GG), blk, 0, stream>>>(
      T_hi, T_lo, 512, 256L * 512, info_hi, info_lo, 512, 256L * 512,
      S, nullptr, 256, 256L * 256, nullptr, 512, lengths);

  softmax_kernel<<<dim3(M / 4), blk, 0, stream>>>(S, P, lengths);

  // ctx[g] = P[g] @ V[g], skip masked row blocks
  gemm_bt<128, false, false, 1, false, 2><<<dim3(4, 2, GG), blk, 0, stream>>>(
      P, nullptr, 256, 256L * 256, Vt, nullptr, 256, 512L * 256,
      ctx, nullptr, 512, 256L * 512, nullptr, 256, lengths);

  // MLP (skip fully-masked row blocks)
  gemm_bt<128, false, false, 1, true, 1><<<dim3(2, M / 128, 1), blk, 0, stream>>>(
      ctx, nullptr, 512, 0, W1t, nullptr, 512, 0, h1, nullptr, 256, 0, b1, 512, lengths);
  gemm_bt<128, false, false, 1, true, 1><<<dim3(1, M / 128, 1), blk, 0, stream>>>(
      h1, nullptr, 256, 0, W2t, nullptr, 256, 0, h2, nullptr, 128, 0, b2, 256, lengths);
  gemm_bt<64, false, false, 1, true, 1><<<dim3(1, M / 128, 1), blk, 0, stream>>>(
      h2, nullptr, 128, 0, W3t, nullptr, 128, 0, h3, nullptr, 64, 0, b3, 128, lengths);

  score_kernel<<<dim3(M / 256), blk, 0, stream>>>(h3, W4, b4, lengths, w);
  out_kernel<<<dim3(GG, SS / 4), blk, 0, stream>>>(raw, w, out);
}

// Round 6
// 302.675 us; speedup vs baseline: 8.9547x; 1.4394x over previous
//
#include <hip/hip_runtime.h>
#include <hip/hip_bf16.h>
#include <cstdint>
#include <cmath>

#define GG 128
#define SS 2048
#define LL 256
#define FF 512
#define DD 512

typedef __bf16 bf16_t;
typedef __bf16 bf16x8 __attribute__((ext_vector_type(8)));
typedef __bf16 bf16x4 __attribute__((ext_vector_type(4)));
typedef float  f32x4  __attribute__((ext_vector_type(4)));

#define MiB (1024UL * 1024UL)
// ---------------- workspace layout (~198 MiB peak) ----------------
#define OFF_INFO_HI (0 * MiB)     // bf16 [32768][512]; later ctx bf16 [32768][512]
#define OFF_INFO_LO (32 * MiB)    // bf16 [32768][512]; later h1/h2/h3
#define OFF_T_HI    (64 * MiB)    // bf16 [32768][512]; later P bf16 [32768][256]
#define OFF_T_LO    (96 * MiB)
#define OFF_S       (128 * MiB)   // fp32 [32768][256]
#define OFF_VT      (160 * MiB)   // bf16 [128][512][256]
#define OFF_WQ_HI   (192 * MiB)
#define OFF_WQ_LO   (192 * MiB + 512 * 1024)
#define OFF_WK_HI   (193 * MiB)
#define OFF_WK_LO   (193 * MiB + 512 * 1024)
#define OFF_GT_HI   (194 * MiB)
#define OFF_GT_LO   (194 * MiB + 512 * 1024)
#define OFF_WVT     (195 * MiB)
#define OFF_W1T     (195 * MiB + 512 * 1024)
#define OFF_W2T     (196 * MiB)
#define OFF_W3T     (196 * MiB + 128 * 1024)
#define OFF_WVEC    (197 * MiB)
// overlays
#define OFF_CTX     OFF_INFO_HI
#define OFF_H1      OFF_INFO_LO            // bf16 [32768][256] (16 MiB)
#define OFF_H2      (OFF_INFO_LO + 16 * MiB)
#define OFF_H3      (OFF_INFO_LO + 24 * MiB)
#define OFF_P       OFF_T_HI               // bf16 [32768][256]

// direct-to-LDS 16B load: wave-uniform LDS base + lane*16 implicit
__device__ __forceinline__ void gload16(const bf16_t* g, bf16_t* lds) {
  __builtin_amdgcn_global_load_lds(
      (const __attribute__((address_space(1))) void*)g,
      (__attribute__((address_space(3))) void*)lds, 16, 0, 0);
}

// ---------------------------------------------------------------------------
// fp32 -> (hi, lo) split cast, unconditional (determinism: every ws byte
// that downstream kernels read must be written in-call)
// ---------------------------------------------------------------------------
__global__ __launch_bounds__(256) void cast_split_kernel(
    const float* __restrict__ in, bf16_t* __restrict__ hi,
    bf16_t* __restrict__ lo) {
  int i = blockIdx.x * 256 + threadIdx.x;
  float4 v = *(const float4*)&in[(size_t)i * 4];
  float x[4] = {v.x, v.y, v.z, v.w};
  bf16x4 h, l;
#pragma unroll
  for (int e = 0; e < 4; ++e) {
    h[e] = (bf16_t)x[e];
    l[e] = (bf16_t)(x[e] - (float)h[e]);
  }
  *(bf16x4*)&hi[(size_t)i * 4] = h;
  *(bf16x4*)&lo[(size_t)i * 4] = l;
}

// ---------------------------------------------------------------------------
// fused weight prep: Wq/Wk split-cast; Wv/W1/W2/W3 transposed cast
// grid = 256 + 256 + 1024 + 512 + 128 + 32 = 2208 blocks
// ---------------------------------------------------------------------------
__global__ __launch_bounds__(256) void prep_weights_kernel(
    const float* __restrict__ Wq, const float* __restrict__ Wk,
    const float* __restrict__ Wv, const float* __restrict__ W1,
    const float* __restrict__ W2, const float* __restrict__ W3,
    bf16_t* __restrict__ Wq_hi, bf16_t* __restrict__ Wq_lo,
    bf16_t* __restrict__ Wk_hi, bf16_t* __restrict__ Wk_lo,
    bf16_t* __restrict__ Wvt, bf16_t* __restrict__ W1t,
    bf16_t* __restrict__ W2t, bf16_t* __restrict__ W3t) {
  const int b = blockIdx.x, t = threadIdx.x;
  if (b < 512) {  // Wq (b<256) / Wk split cast, float4-granular
    const float* src = (b < 256) ? Wq : Wk;
    bf16_t* dhi = (b < 256) ? Wq_hi : Wk_hi;
    bf16_t* dlo = (b < 256) ? Wq_lo : Wk_lo;
    int i = (b & 255) * 256 + t;
    float4 v = *(const float4*)&src[(size_t)i * 4];
    float x[4] = {v.x, v.y, v.z, v.w};
    bf16x4 h, l;
#pragma unroll
    for (int e = 0; e < 4; ++e) {
      h[e] = (bf16_t)x[e];
      l[e] = (bf16_t)(x[e] - (float)h[e]);
    }
    *(bf16x4*)&dhi[(size_t)i * 4] = h;
    *(bf16x4*)&dlo[(size_t)i * 4] = l;
  } else if (b < 1536) {  // Wvt[c][r] = Wv[r][c], 512x512
    int i = (b - 512) * 256 + t;
    int r = i >> 9, c = i & 511;
    Wvt[(size_t)c * 512 + r] = (bf16_t)Wv[i];
  } else if (b < 2048) {  // W1t, 512x256
    int i = (b - 1536) * 256 + t;
    int r = i >> 8, c = i & 255;
    W1t[(size_t)c * 512 + r] = (bf16_t)W1[i];
  } else if (b < 2176) {  // W2t, 256x128
    int i = (b - 2048) * 256 + t;
    int r = i >> 7, c = i & 127;
    W2t[(size_t)c * 256 + r] = (bf16_t)W2[i];
  } else {  // W3t, 128x64
    int i = (b - 2176) * 256 + t;
    int r = i >> 6, c = i & 63;
    W3t[(size_t)c * 128 + r] = (bf16_t)W3[i];
  }
}

// ---------------------------------------------------------------------------
// gemm_bt: C[b] = A[b] @ Bt[b]^T (+bias). Split-bf16 3-term when A/BSPLIT.
// BM=128, BK=64, 256 threads (4 waves 2x2), MFMA 16x16x32.
// Staging: global_load_lds width=16, XOR swizzle applied on the SOURCE
// address (involution) so LDS dest stays linear (rule 21). Explicit
// vmcnt(0) drain before the barrier (race-proof regardless of compiler
// lowering of __syncthreads for direct-to-LDS loads).
// OUTMODE: 0 fp32, 1 bf16, 2 split bf16 (hi->C0, lo->C1),
//          3 bf16 transposed into Vt[g][col][row&255]
// SKIP: 0 none; 1 global-M rows ((m0&255)>=n); 2 batched rows (m0>=n);
//       3 batched rows+cols (also n0>=n)
// ---------------------------------------------------------------------------
template <int BN, bool ASPLIT, bool BSPLIT, int OUTMODE, bool BIAS, int SKIP>
__global__ __launch_bounds__(256) void gemm_bt(
    const bf16_t* __restrict__ Ahi, const bf16_t* __restrict__ Alo, int lda, long sA,
    const bf16_t* __restrict__ Bhi, const bf16_t* __restrict__ Blo, int ldb, long sB,
    void* __restrict__ C0, void* __restrict__ C1, int ldc, long sC,
    const float* __restrict__ bias, int K, const int* __restrict__ lengths) {
  constexpr int BM = 128;
  constexpr int BK = 64;
  constexpr int WM = 4;
  constexpr int WN = BN / 32;
  constexpr int PA = BM * BK;
  constexpr int PB = BN * BK;
  constexpr int ITA = BM * 8 / 256;   // 4
  constexpr int ITB = BN * 8 / 256;   // 4 (BN=128) or 2 (BN=64)
  __shared__ bf16_t As[(ASPLIT ? 2 : 1) * PA];
  __shared__ bf16_t Bs[(BSPLIT ? 2 : 1) * PB];

  const int m0 = blockIdx.y * BM;
  const int n0 = blockIdx.x * BN;
  const int b  = blockIdx.z;

  if (SKIP == 1) { if ((m0 & 255) >= lengths[m0 >> 8]) return; }
  if (SKIP == 2) { if (m0 >= lengths[b]) return; }
  if (SKIP == 3) { int n = lengths[b]; if (m0 >= n || n0 >= n) return; }

  const int t = threadIdx.x;
  const int lane = t & 63;
  const int wave = t >> 6;
  const int wm = (wave >> 1) * 64;
  const int wn = (wave & 1) * (BN / 2);

  const bf16_t* Ah = Ahi + (size_t)b * sA;
  const bf16_t* Al = ASPLIT ? Alo + (size_t)b * sA : nullptr;
  const bf16_t* Bh = Bhi + (size_t)b * sB;
  const bf16_t* Bl = BSPLIT ? Blo + (size_t)b * sB : nullptr;

  f32x4 acc[WM][WN];
#pragma unroll
  for (int i = 0; i < WM; ++i)
#pragma unroll
    for (int j = 0; j < WN; ++j) acc[i][j] = {0.f, 0.f, 0.f, 0.f};

  const int fr = lane & 15;
  const int fs = lane >> 4;
  // staging source indices (constant across k-steps)
  const int sr = t >> 3, ssl = t & 7;

  for (int k0 = 0; k0 < K; k0 += BK) {
#pragma unroll
    for (int it = 0; it < ITA; ++it) {
      const int r = sr + it * 32;                     // (t + it*256)>>3
      const size_t ga = (size_t)(m0 + r) * lda + k0 + ((ssl ^ (r & 7)) << 3);
      bf16_t* dst = &As[(it * 256 + wave * 64) * 8];  // wave-uniform
      gload16(&Ah[ga], dst);
      if (ASPLIT) gload16(&Al[ga], dst + PA);
    }
#pragma unroll
    for (int it = 0; it < ITB; ++it) {
      const int r = sr + it * 32;
      const size_t ga = (size_t)(n0 + r) * ldb + k0 + ((ssl ^ (r & 7)) << 3);
      bf16_t* dst = &Bs[(it * 256 + wave * 64) * 8];
      gload16(&Bh[ga], dst);
      if (BSPLIT) gload16(&Bl[ga], dst + PB);
    }
    // explicit drain: do NOT rely on __syncthreads() lowering to wait on
    // direct-to-LDS DMA completion
    asm volatile("s_waitcnt vmcnt(0)" ::: "memory");
    __builtin_amdgcn_sched_barrier(0);
    __syncthreads();
#pragma unroll
    for (int kk = 0; kk < 2; ++kk) {
      bf16x8 ah[WM], al[WM], bh[WN], bl[WN];
#pragma unroll
      for (int i = 0; i < WM; ++i) {
        int r = wm + i * 16 + fr;
        int la = r * BK + (((kk * 4 + fs) ^ (r & 7)) * 8);
        ah[i] = *(const bf16x8*)&As[la];
        if (ASPLIT) al[i] = *(const bf16x8*)&As[PA + la];
      }
#pragma unroll
      for (int j = 0; j < WN; ++j) {
        int r = wn + j * 16 + fr;
        int la = r * BK + (((kk * 4 + fs) ^ (r & 7)) * 8);
        bh[j] = *(const bf16x8*)&Bs[la];
        if (BSPLIT) bl[j] = *(const bf16x8*)&Bs[PB + la];
      }
#pragma unroll
      for (int i = 0; i < WM; ++i)
#pragma unroll
        for (int j = 0; j < WN; ++j) {
          acc[i][j] = __builtin_amdgcn_mfma_f32_16x16x32_bf16(ah[i], bh[j], acc[i][j], 0, 0, 0);
          if (BSPLIT)
            acc[i][j] = __builtin_amdgcn_mfma_f32_16x16x32_bf16(ah[i], bl[j], acc[i][j], 0, 0, 0);
          if (ASPLIT)
            acc[i][j] = __builtin_amdgcn_mfma_f32_16x16x32_bf16(al[i], bh[j], acc[i][j], 0, 0, 0);
        }
    }
    __syncthreads();
  }

#pragma unroll
  for (int i = 0; i < WM; ++i) {
#pragma unroll
    for (int j = 0; j < WN; ++j) {
      const int col = n0 + wn + j * 16 + fr;
      if (OUTMODE == 3) {
        // Vt[g][col][row&255], 4 consecutive rows -> one 8B store
        const int row = m0 + wm + i * 16 + fs * 4;
        bf16x4 vv;
#pragma unroll
        for (int jj = 0; jj < 4; ++jj) vv[jj] = (bf16_t)acc[i][j][jj];
        *(bf16x4*)&((bf16_t*)C0)[((size_t)(row >> 8) * 512 + col) * 256 + (row & 255)] = vv;
      } else {
        float bv = 0.f;
        if (BIAS) bv = bias[col];
#pragma unroll
        for (int jj = 0; jj < 4; ++jj) {
          const int row = m0 + wm + i * 16 + fs * 4 + jj;
          const float v = acc[i][j][jj] + bv;
          const size_t off = (size_t)b * sC + (size_t)row * ldc + col;
          if (OUTMODE == 0) {
            ((float*)C0)[off] = v;
          } else if (OUTMODE == 1) {
            ((bf16_t*)C0)[off] = (bf16_t)v;
          } else {
            bf16_t h = (bf16_t)v;
            ((bf16_t*)C0)[off] = h;
            ((bf16_t*)C1)[off] = (bf16_t)(v - (float)h);
          }
        }
      }
    }
  }
}

// ---------------------------------------------------------------------------
// masked softmax: S fp32 -> P bf16, one wave per row.
// Invalid rows (l >= n) get an explicit ZERO row (determinism: the ctx GEMM
// stages these rows; they must not be stale ws garbage).
// ---------------------------------------------------------------------------
__global__ __launch_bounds__(256) void softmax_kernel(
    const float* __restrict__ S, bf16_t* __restrict__ P,
    const int* __restrict__ lengths) {
  const int t = threadIdx.x, lane = t & 63, wave = t >> 6;
  const int row = blockIdx.x * 4 + wave;
  const int g = row >> 8;
  const int n = lengths[g];
  const int c0 = lane * 4;
  if ((row & 255) >= n) {
    bf16x4 z = {(bf16_t)0.f, (bf16_t)0.f, (bf16_t)0.f, (bf16_t)0.f};
    *(bf16x4*)&P[(size_t)row * 256 + c0] = z;
    return;
  }
  const float* srow = S + (size_t)row * 256;
  float4 v = *(const float4*)&srow[c0];
  float s[4] = {v.x, v.y, v.z, v.w};
  float m = -INFINITY;
#pragma unroll
  for (int e = 0; e < 4; ++e)
    if (c0 + e < n) m = fmaxf(m, s[e]);
#pragma unroll
  for (int off = 32; off > 0; off >>= 1) m = fmaxf(m, __shfl_xor(m, off));
  float e4[4];
  float sum = 0.f;
#pragma unroll
  for (int e = 0; e < 4; ++e) {
    e4[e] = (c0 + e < n) ? __expf(s[e] - m) : 0.f;
    sum += e4[e];
  }
#pragma unroll
  for (int off = 32; off > 0; off >>= 1) sum += __shfl_xor(sum, off);
  const float inv = 1.f / sum;
  bf16x4 p;
#pragma unroll
  for (int e = 0; e < 4; ++e) p[e] = (bf16_t)(e4[e] * inv);
  *(bf16x4*)&P[(size_t)row * 256 + c0] = p;
}

// ---------------------------------------------------------------------------
// final scorer + length==1 onehot + key-mask zeroing
// ---------------------------------------------------------------------------
__global__ __launch_bounds__(256) void score_kernel(
    const bf16_t* __restrict__ h3, const float* __restrict__ W4,
    const float* __restrict__ b4, const int* __restrict__ lengths,
    float* __restrict__ w) {
  __shared__ float w4[64];
  const int t = threadIdx.x;
  if (t < 64) w4[t] = W4[t];
  __syncthreads();
  const int idx = blockIdx.x * 256 + t;
  const int g = idx >> 8, l = idx & 255;
  const int n = lengths[g];
  float val;
  if (n == 1) {
    val = (l == 0) ? 1.f : 0.f;
  } else if (l >= n) {
    val = 0.f;
  } else {
    const bf16_t* row = h3 + (size_t)idx * 64;
    float acc = b4[0];
#pragma unroll
    for (int k = 0; k < 64; ++k) acc += (float)row[k] * w4[k];
    val = acc;
  }
  w[idx] = val;
}

// ---------------------------------------------------------------------------
// out[s,g] = sum_l raw[g,s,l] * w[g,l]; skips l >= n (w is exactly 0 there)
// ---------------------------------------------------------------------------
__global__ __launch_bounds__(256) void out_kernel(
    const float* __restrict__ raw, const float* __restrict__ w,
    const int* __restrict__ lengths, float* __restrict__ out) {
  __shared__ float wl[LL];
  const int g = blockIdx.x;
  const int t = threadIdx.x;
  wl[t] = w[g * LL + t];
  __syncthreads();
  const int n = lengths[g];
  const int wave = t >> 6, lane = t & 63;
  const int s = blockIdx.y * 4 + wave;
  float acc = 0.f;
  if (lane * 4 < n) {
    const float4 r4 = *(const float4*)(raw + ((size_t)g * SS + s) * LL + lane * 4);
    const float4 w4v = *(const float4*)&wl[lane * 4];
    acc = r4.x * w4v.x + r4.y * w4v.y + r4.z * w4v.z + r4.w * w4v.w;
  }
#pragma unroll
  for (int off = 32; off > 0; off >>= 1) acc += __shfl_down(acc, off);
  if (lane == 0) out[(size_t)s * GG + g] = acc;
}

// ---------------------------------------------------------------------------
extern "C" void kernel_launch(void* const* d_in, const int* in_sizes, int n_in,
                              void* d_out, int out_size, void* d_ws, size_t ws_size,
                              hipStream_t stream) {
  const float* raw  = (const float*)d_in[0];
  const float* info = (const float*)d_in[1];
  const float* Wq   = (const float*)d_in[2];
  const float* Wk   = (const float*)d_in[3];
  const float* Wv   = (const float*)d_in[4];
  const float* W1   = (const float*)d_in[5];
  const float* b1   = (const float*)d_in[6];
  const float* W2   = (const float*)d_in[7];
  const float* b2   = (const float*)d_in[8];
  const float* W3   = (const float*)d_in[9];
  const float* b3   = (const float*)d_in[10];
  const float* W4   = (const float*)d_in[11];
  const float* b4   = (const float*)d_in[12];
  const int* lengths = (const int*)d_in[13];
  float* out = (float*)d_out;

  char* ws = (char*)d_ws;
  bf16_t* info_hi = (bf16_t*)(ws + OFF_INFO_HI);
  bf16_t* info_lo = (bf16_t*)(ws + OFF_INFO_LO);
  bf16_t* T_hi = (bf16_t*)(ws + OFF_T_HI);
  bf16_t* T_lo = (bf16_t*)(ws + OFF_T_LO);
  bf16_t* Vt   = (bf16_t*)(ws + OFF_VT);
  bf16_t* Wq_hi = (bf16_t*)(ws + OFF_WQ_HI);
  bf16_t* Wq_lo = (bf16_t*)(ws + OFF_WQ_LO);
  bf16_t* Wk_hi = (bf16_t*)(ws + OFF_WK_HI);
  bf16_t* Wk_lo = (bf16_t*)(ws + OFF_WK_LO);
  bf16_t* Gt_hi = (bf16_t*)(ws + OFF_GT_HI);
  bf16_t* Gt_lo = (bf16_t*)(ws + OFF_GT_LO);
  bf16_t* Wvt = (bf16_t*)(ws + OFF_WVT);
  bf16_t* W1t = (bf16_t*)(ws + OFF_W1T);
  bf16_t* W2t = (bf16_t*)(ws + OFF_W2T);
  bf16_t* W3t = (bf16_t*)(ws + OFF_W3T);
  float*  S   = (float*)(ws + OFF_S);
  bf16_t* ctx = (bf16_t*)(ws + OFF_CTX);
  bf16_t* P   = (bf16_t*)(ws + OFF_P);
  bf16_t* h1  = (bf16_t*)(ws + OFF_H1);
  bf16_t* h2  = (bf16_t*)(ws + OFF_H2);
  bf16_t* h3  = (bf16_t*)(ws + OFF_H3);
  float*  w   = (float*)(ws + OFF_WVEC);

  dim3 blk(256);
  const int M = GG * LL;  // 32768

  // preparation
  prep_weights_kernel<<<dim3(2208), blk, 0, stream>>>(
      Wq, Wk, Wv, W1, W2, W3, Wq_hi, Wq_lo, Wk_hi, Wk_lo, Wvt, W1t, W2t, W3t);
  cast_split_kernel<<<dim3(M * FF / 4 / 256), blk, 0, stream>>>(info, info_hi, info_lo);

  // Gt = Wk @ Wq^T (split) so that Gt^T = G = Wq @ Wk^T
  gemm_bt<128, true, true, 2, false, 0><<<dim3(4, 4, 1), blk, 0, stream>>>(
      Wk_hi, Wk_lo, 512, 0, Wq_hi, Wq_lo, 512, 0, Gt_hi, Gt_lo, 512, 0, nullptr, 512, nullptr);

  // T = info @ G (split out), skip fully-masked row blocks
  gemm_bt<128, true, true, 2, false, 1><<<dim3(4, M / 128, 1), blk, 0, stream>>>(
      info_hi, info_lo, 512, 0, Gt_hi, Gt_lo, 512, 0, T_hi, T_lo, 512, 0, nullptr, 512, lengths);

  // V = info @ Wv, written directly transposed into Vt
  gemm_bt<128, false, false, 3, false, 1><<<dim3(4, M / 128, 1), blk, 0, stream>>>(
      info_hi, nullptr, 512, 0, Wvt, nullptr, 512, 0, Vt, nullptr, 0, 0, nullptr, 512, lengths);

  // S[g] = T[g] @ info[g]^T (3-term split -> fp32), skip masked row/col tiles
  gemm_bt<128, true, true, 0, false, 3><<<dim3(2, 2, GG), blk, 0, stream>>>(
      T_hi, T_lo, 512, 256L * 512, info_hi, info_lo, 512, 256L * 512,
      S, nullptr, 256, 256L * 256, nullptr, 512, lengths);

  softmax_kernel<<<dim3(M / 4), blk, 0, stream>>>(S, P, lengths);

  // ctx[g] = P[g] @ V[g], skip masked row blocks
  gemm_bt<128, false, false, 1, false, 2><<<dim3(4, 2, GG), blk, 0, stream>>>(
      P, nullptr, 256, 256L * 256, Vt, nullptr, 256, 512L * 256,
      ctx, nullptr, 512, 256L * 512, nullptr, 256, lengths);

  // MLP (skip fully-masked row blocks)
  gemm_bt<128, false, false, 1, true, 1><<<dim3(2, M / 128, 1), blk, 0, stream>>>(
      ctx, nullptr, 512, 0, W1t, nullptr, 512, 0, h1, nullptr, 256, 0, b1, 512, lengths);
  gemm_bt<128, false, false, 1, true, 1><<<dim3(1, M / 128, 1), blk, 0, stream>>>(
      h1, nullptr, 256, 0, W2t, nullptr, 256, 0, h2, nullptr, 128, 0, b2, 256, lengths);
  gemm_bt<64, false, false, 1, true, 1><<<dim3(1, M / 128, 1), blk, 0, stream>>>(
      h2, nullptr, 128, 0, W3t, nullptr, 128, 0, h3, nullptr, 64, 0, b3, 128, lengths);

  score_kernel<<<dim3(M / 256), blk, 0, stream>>>(h3, W4, b4, lengths, w);
  out_kernel<<<dim3(GG, SS / 4), blk, 0, stream>>>(raw, w, lengths, out);
}

// Round 7
// 296.264 us; speedup vs baseline: 9.1485x; 1.0216x over previous
//
#include <hip/hip_runtime.h>
#include <hip/hip_bf16.h>
#include <cstdint>
#include <cmath>

#define GG 128
#define SS 2048
#define LL 256
#define FF 512
#define DD 512

typedef __bf16 bf16_t;
typedef __bf16 bf16x8 __attribute__((ext_vector_type(8)));
typedef __bf16 bf16x4 __attribute__((ext_vector_type(4)));
typedef float  f32x4  __attribute__((ext_vector_type(4)));

#define MiB (1024UL * 1024UL)
// ---------------- workspace layout (~167 MiB peak) ----------------
#define OFF_INFO_HI (0 * MiB)     // bf16 [32768][512]
#define OFF_INFO_LO (32 * MiB)    // bf16 [32768][512]
#define OFF_T_HI    (64 * MiB)    // bf16 [32768][512]
#define OFF_T_LO    (96 * MiB)
#define OFF_S       (128 * MiB)   // fp32 [32768][256] (32 MiB)
#define OFF_WQ_HI   (160 * MiB)
#define OFF_WQ_LO   (160 * MiB + 512 * 1024)
#define OFF_WK_HI   (161 * MiB)
#define OFF_WK_LO   (161 * MiB + 512 * 1024)
#define OFF_GT_HI   (162 * MiB)
#define OFF_GT_LO   (162 * MiB + 512 * 1024)
#define OFF_VEFF    (163 * MiB)   // fp32 [32768] (128 KiB)
#define OFF_VW      (164 * MiB)   // fp32 [512] vweff = Wv @ u
#define OFF_CC      (164 * MiB + 4096) // fp32 [1] folded bias c0
#define OFF_WVEC    (165 * MiB)   // fp32 [32768] final weights

// direct-to-LDS 16B load: wave-uniform LDS base + lane*16 implicit
__device__ __forceinline__ void gload16(const bf16_t* g, bf16_t* lds) {
  __builtin_amdgcn_global_load_lds(
      (const __attribute__((address_space(1))) void*)g,
      (__attribute__((address_space(3))) void*)lds, 16, 0, 0);
}

// ---------------------------------------------------------------------------
// fp32 -> (hi, lo) split cast, unconditional (determinism: every ws byte
// read downstream must be written in-call)
// ---------------------------------------------------------------------------
__global__ __launch_bounds__(256) void cast_split_kernel(
    const float* __restrict__ in, bf16_t* __restrict__ hi,
    bf16_t* __restrict__ lo) {
  int i = blockIdx.x * 256 + threadIdx.x;
  float4 v = *(const float4*)&in[(size_t)i * 4];
  float x[4] = {v.x, v.y, v.z, v.w};
  bf16x4 h, l;
#pragma unroll
  for (int e = 0; e < 4; ++e) {
    h[e] = (bf16_t)x[e];
    l[e] = (bf16_t)(x[e] - (float)h[e]);
  }
  *(bf16x4*)&hi[(size_t)i * 4] = h;
  *(bf16x4*)&lo[(size_t)i * 4] = l;
}

// ---------------------------------------------------------------------------
// Wq / Wk split cast (grid = 512 blocks)
// ---------------------------------------------------------------------------
__global__ __launch_bounds__(256) void prep_qk_kernel(
    const float* __restrict__ Wq, const float* __restrict__ Wk,
    bf16_t* __restrict__ Wq_hi, bf16_t* __restrict__ Wq_lo,
    bf16_t* __restrict__ Wk_hi, bf16_t* __restrict__ Wk_lo) {
  const int b = blockIdx.x, t = threadIdx.x;
  const float* src = (b < 256) ? Wq : Wk;
  bf16_t* dhi = (b < 256) ? Wq_hi : Wk_hi;
  bf16_t* dlo = (b < 256) ? Wq_lo : Wk_lo;
  int i = (b & 255) * 256 + t;
  float4 v = *(const float4*)&src[(size_t)i * 4];
  float x[4] = {v.x, v.y, v.z, v.w};
  bf16x4 h, l;
#pragma unroll
  for (int e = 0; e < 4; ++e) {
    h[e] = (bf16_t)x[e];
    l[e] = (bf16_t)(x[e] - (float)h[e]);
  }
  *(bf16x4*)&dhi[(size_t)i * 4] = h;
  *(bf16x4*)&dlo[(size_t)i * 4] = l;
}

// ---------------------------------------------------------------------------
// fold the linear scorer: u = W1@W2@W3@W4 (512), vweff = Wv@u (512),
// c0 = ((b1@W2+b2)@W3+b3)@W4 + b4.  One block, 256 threads, fp32 exact.
// ---------------------------------------------------------------------------
__global__ __launch_bounds__(256) void chain_kernel(
    const float* __restrict__ Wv, const float* __restrict__ W1,
    const float* __restrict__ b1, const float* __restrict__ W2,
    const float* __restrict__ b2, const float* __restrict__ W3,
    const float* __restrict__ b3, const float* __restrict__ W4,
    const float* __restrict__ b4,
    float* __restrict__ vweff, float* __restrict__ cc) {
  __shared__ float v34[128], v234[256], u[512], t2[128], t3[64];
  const int t = threadIdx.x;
  if (t < 128) {  // v34 = W3 @ W4
    float a = 0.f;
    for (int k = 0; k < 64; ++k) a += W3[t * 64 + k] * W4[k];
    v34[t] = a;
  }
  __syncthreads();
  {  // v234 = W2 @ v34
    float a = 0.f;
    for (int k = 0; k < 128; ++k) a += W2[t * 128 + k] * v34[k];
    v234[t] = a;
  }
  __syncthreads();
#pragma unroll
  for (int h = 0; h < 2; ++h) {  // u = W1 @ v234
    int i = h * 256 + t;
    float a = 0.f;
    for (int k = 0; k < 256; ++k) a += W1[i * 256 + k] * v234[k];
    u[i] = a;
  }
  __syncthreads();
#pragma unroll
  for (int h = 0; h < 2; ++h) {  // vweff = Wv @ u
    int i = h * 256 + t;
    float a = 0.f;
    for (int k = 0; k < 512; ++k) a += Wv[(size_t)i * 512 + k] * u[k];
    vweff[i] = a;
  }
  // bias chain
  if (t < 128) {  // t2 = b1@W2 + b2
    float a = b2[t];
    for (int i = 0; i < 256; ++i) a += b1[i] * W2[i * 128 + t];
    t2[t] = a;
  }
  __syncthreads();
  if (t < 64) {  // t3 = t2@W3 + b3
    float a = b3[t];
    for (int i = 0; i < 128; ++i) a += t2[i] * W3[i * 64 + t];
    t3[t] = a;
  }
  __syncthreads();
  if (t == 0) {
    float a = b4[0];
    for (int j = 0; j < 64; ++j) a += t3[j] * W4[j];
    cc[0] = a;
  }
}

// ---------------------------------------------------------------------------
// veff[row] = info[row,:] . vweff  (fp32, from raw fp32 info);
// masked rows (l >= n) get explicit 0.
// ---------------------------------------------------------------------------
__global__ __launch_bounds__(256) void veff_kernel(
    const float* __restrict__ info, const float* __restrict__ vweff,
    const int* __restrict__ lengths, float* __restrict__ veff) {
  __shared__ float vw[512];
  const int t = threadIdx.x;
  vw[t] = vweff[t];
  vw[256 + t] = vweff[256 + t];
  __syncthreads();
  const int lane = t & 63, wave = t >> 6;
  const int row = blockIdx.x * 4 + wave;
  const int n = lengths[row >> 8];
  if ((row & 255) >= n) {
    if (lane == 0) veff[row] = 0.f;
    return;
  }
  const float* ip = info + (size_t)row * 512 + lane * 8;
  const float4 a = *(const float4*)ip;
  const float4 b = *(const float4*)(ip + 4);
  const int d0 = lane * 8;
  float acc = a.x * vw[d0] + a.y * vw[d0 + 1] + a.z * vw[d0 + 2] + a.w * vw[d0 + 3] +
              b.x * vw[d0 + 4] + b.y * vw[d0 + 5] + b.z * vw[d0 + 6] + b.w * vw[d0 + 7];
#pragma unroll
  for (int off = 32; off > 0; off >>= 1) acc += __shfl_down(acc, off);
  if (lane == 0) veff[row] = acc;
}

// ---------------------------------------------------------------------------
// gemm_bt: C[b] = A[b] @ Bt[b]^T. Split-bf16 3-term when A/BSPLIT.
// BM=128, BK=64, 256 threads (4 waves 2x2), MFMA 16x16x32.
// Staging: global_load_lds width=16, XOR swizzle on SOURCE address
// (involution, rule 21); explicit vmcnt(0) drain before barrier.
// OUTMODE: 0 fp32, 2 split bf16 (hi->C0, lo->C1)
// SKIP: 0 none; 1 global-M rows ((m0&255)>=n); 3 batched rows+cols
// ---------------------------------------------------------------------------
template <int BN, bool ASPLIT, bool BSPLIT, int OUTMODE, int SKIP>
__global__ __launch_bounds__(256) void gemm_bt(
    const bf16_t* __restrict__ Ahi, const bf16_t* __restrict__ Alo, int lda, long sA,
    const bf16_t* __restrict__ Bhi, const bf16_t* __restrict__ Blo, int ldb, long sB,
    void* __restrict__ C0, void* __restrict__ C1, int ldc, long sC,
    int K, const int* __restrict__ lengths) {
  constexpr int BM = 128;
  constexpr int BK = 64;
  constexpr int WM = 4;
  constexpr int WN = BN / 32;
  constexpr int PA = BM * BK;
  constexpr int PB = BN * BK;
  constexpr int ITA = BM * 8 / 256;
  constexpr int ITB = BN * 8 / 256;
  __shared__ bf16_t As[(ASPLIT ? 2 : 1) * PA];
  __shared__ bf16_t Bs[(BSPLIT ? 2 : 1) * PB];

  const int m0 = blockIdx.y * BM;
  const int n0 = blockIdx.x * BN;
  const int b  = blockIdx.z;

  if (SKIP == 1) { if ((m0 & 255) >= lengths[m0 >> 8]) return; }
  if (SKIP == 3) { int n = lengths[b]; if (m0 >= n || n0 >= n) return; }

  const int t = threadIdx.x;
  const int lane = t & 63;
  const int wave = t >> 6;
  const int wm = (wave >> 1) * 64;
  const int wn = (wave & 1) * (BN / 2);

  const bf16_t* Ah = Ahi + (size_t)b * sA;
  const bf16_t* Al = ASPLIT ? Alo + (size_t)b * sA : nullptr;
  const bf16_t* Bh = Bhi + (size_t)b * sB;
  const bf16_t* Bl = BSPLIT ? Blo + (size_t)b * sB : nullptr;

  f32x4 acc[WM][WN];
#pragma unroll
  for (int i = 0; i < WM; ++i)
#pragma unroll
    for (int j = 0; j < WN; ++j) acc[i][j] = {0.f, 0.f, 0.f, 0.f};

  const int fr = lane & 15;
  const int fs = lane >> 4;
  const int sr = t >> 3, ssl = t & 7;

  for (int k0 = 0; k0 < K; k0 += BK) {
#pragma unroll
    for (int it = 0; it < ITA; ++it) {
      const int r = sr + it * 32;
      const size_t ga = (size_t)(m0 + r) * lda + k0 + ((ssl ^ (r & 7)) << 3);
      bf16_t* dst = &As[(it * 256 + wave * 64) * 8];
      gload16(&Ah[ga], dst);
      if (ASPLIT) gload16(&Al[ga], dst + PA);
    }
#pragma unroll
    for (int it = 0; it < ITB; ++it) {
      const int r = sr + it * 32;
      const size_t ga = (size_t)(n0 + r) * ldb + k0 + ((ssl ^ (r & 7)) << 3);
      bf16_t* dst = &Bs[(it * 256 + wave * 64) * 8];
      gload16(&Bh[ga], dst);
      if (BSPLIT) gload16(&Bl[ga], dst + PB);
    }
    asm volatile("s_waitcnt vmcnt(0)" ::: "memory");
    __builtin_amdgcn_sched_barrier(0);
    __syncthreads();
#pragma unroll
    for (int kk = 0; kk < 2; ++kk) {
      bf16x8 ah[WM], al[WM], bh[WN], bl[WN];
#pragma unroll
      for (int i = 0; i < WM; ++i) {
        int r = wm + i * 16 + fr;
        int la = r * BK + (((kk * 4 + fs) ^ (r & 7)) * 8);
        ah[i] = *(const bf16x8*)&As[la];
        if (ASPLIT) al[i] = *(const bf16x8*)&As[PA + la];
      }
#pragma unroll
      for (int j = 0; j < WN; ++j) {
        int r = wn + j * 16 + fr;
        int la = r * BK + (((kk * 4 + fs) ^ (r & 7)) * 8);
        bh[j] = *(const bf16x8*)&Bs[la];
        if (BSPLIT) bl[j] = *(const bf16x8*)&Bs[PB + la];
      }
#pragma unroll
      for (int i = 0; i < WM; ++i)
#pragma unroll
        for (int j = 0; j < WN; ++j) {
          acc[i][j] = __builtin_amdgcn_mfma_f32_16x16x32_bf16(ah[i], bh[j], acc[i][j], 0, 0, 0);
          if (BSPLIT)
            acc[i][j] = __builtin_amdgcn_mfma_f32_16x16x32_bf16(ah[i], bl[j], acc[i][j], 0, 0, 0);
          if (ASPLIT)
            acc[i][j] = __builtin_amdgcn_mfma_f32_16x16x32_bf16(al[i], bh[j], acc[i][j], 0, 0, 0);
        }
    }
    __syncthreads();
  }

#pragma unroll
  for (int i = 0; i < WM; ++i) {
#pragma unroll
    for (int j = 0; j < WN; ++j) {
      const int col = n0 + wn + j * 16 + fr;
#pragma unroll
      for (int jj = 0; jj < 4; ++jj) {
        const int row = m0 + wm + i * 16 + fs * 4 + jj;
        const float v = acc[i][j][jj];
        const size_t off = (size_t)b * sC + (size_t)row * ldc + col;
        if (OUTMODE == 0) {
          ((float*)C0)[off] = v;
        } else {
          bf16_t h = (bf16_t)v;
          ((bf16_t*)C0)[off] = h;
          ((bf16_t*)C1)[off] = (bf16_t)(v - (float)h);
        }
      }
    }
  }
}

// ---------------------------------------------------------------------------
// fused masked softmax + scorer: w[row] = (sum_m exp(S-m)*veff) / sum + c0,
// with length==1 onehot and key/query masking. One wave per row; P never
// materialized.  All 32768 w entries written (determinism).
// ---------------------------------------------------------------------------
__global__ __launch_bounds__(256) void softmax_dot_kernel(
    const float* __restrict__ S, const float* __restrict__ veff,
    const float* __restrict__ cc, const int* __restrict__ lengths,
    float* __restrict__ w) {
  const int t = threadIdx.x, lane = t & 63, wave = t >> 6;
  const int row = blockIdx.x * 4 + wave;
  const int g = row >> 8, l = row & 255;
  const int n = lengths[g];
  if (n == 1 || l >= n) {
    if (lane == 0) w[row] = (n == 1 && l == 0) ? 1.f : 0.f;
    return;
  }
  const float* srow = S + (size_t)row * 256;
  const int c0i = lane * 4;
  float4 v = *(const float4*)&srow[c0i];
  float s[4] = {v.x, v.y, v.z, v.w};
  float m = -INFINITY;
#pragma unroll
  for (int e = 0; e < 4; ++e)
    if (c0i + e < n) m = fmaxf(m, s[e]);
#pragma unroll
  for (int off = 32; off > 0; off >>= 1) m = fmaxf(m, __shfl_xor(m, off));
  float sum = 0.f, dot = 0.f;
#pragma unroll
  for (int e = 0; e < 4; ++e) {
    if (c0i + e < n) {
      float ee = __expf(s[e] - m);
      sum += ee;
      dot += ee * veff[g * 256 + c0i + e];
    }
  }
#pragma unroll
  for (int off = 32; off > 0; off >>= 1) {
    sum += __shfl_xor(sum, off);
    dot += __shfl_xor(dot, off);
  }
  if (lane == 0) w[row] = dot / sum + cc[0];
}

// ---------------------------------------------------------------------------
// out[s,g] = sum_l raw[g,s,l] * w[g,l]; skips l >= n (w is exactly 0 there)
// ---------------------------------------------------------------------------
__global__ __launch_bounds__(256) void out_kernel(
    const float* __restrict__ raw, const float* __restrict__ w,
    const int* __restrict__ lengths, float* __restrict__ out) {
  __shared__ float wl[LL];
  const int g = blockIdx.x;
  const int t = threadIdx.x;
  wl[t] = w[g * LL + t];
  __syncthreads();
  const int n = lengths[g];
  const int wave = t >> 6, lane = t & 63;
  const int s = blockIdx.y * 4 + wave;
  float acc = 0.f;
  if (lane * 4 < n) {
    const float4 r4 = *(const float4*)(raw + ((size_t)g * SS + s) * LL + lane * 4);
    const float4 w4v = *(const float4*)&wl[lane * 4];
    acc = r4.x * w4v.x + r4.y * w4v.y + r4.z * w4v.z + r4.w * w4v.w;
  }
#pragma unroll
  for (int off = 32; off > 0; off >>= 1) acc += __shfl_down(acc, off);
  if (lane == 0) out[(size_t)s * GG + g] = acc;
}

// ---------------------------------------------------------------------------
extern "C" void kernel_launch(void* const* d_in, const int* in_sizes, int n_in,
                              void* d_out, int out_size, void* d_ws, size_t ws_size,
                              hipStream_t stream) {
  const float* raw  = (const float*)d_in[0];
  const float* info = (const float*)d_in[1];
  const float* Wq   = (const float*)d_in[2];
  const float* Wk   = (const float*)d_in[3];
  const float* Wv   = (const float*)d_in[4];
  const float* W1   = (const float*)d_in[5];
  const float* b1   = (const float*)d_in[6];
  const float* W2   = (const float*)d_in[7];
  const float* b2   = (const float*)d_in[8];
  const float* W3   = (const float*)d_in[9];
  const float* b3   = (const float*)d_in[10];
  const float* W4   = (const float*)d_in[11];
  const float* b4   = (const float*)d_in[12];
  const int* lengths = (const int*)d_in[13];
  float* out = (float*)d_out;

  char* ws = (char*)d_ws;
  bf16_t* info_hi = (bf16_t*)(ws + OFF_INFO_HI);
  bf16_t* info_lo = (bf16_t*)(ws + OFF_INFO_LO);
  bf16_t* T_hi = (bf16_t*)(ws + OFF_T_HI);
  bf16_t* T_lo = (bf16_t*)(ws + OFF_T_LO);
  bf16_t* Wq_hi = (bf16_t*)(ws + OFF_WQ_HI);
  bf16_t* Wq_lo = (bf16_t*)(ws + OFF_WQ_LO);
  bf16_t* Wk_hi = (bf16_t*)(ws + OFF_WK_HI);
  bf16_t* Wk_lo = (bf16_t*)(ws + OFF_WK_LO);
  bf16_t* Gt_hi = (bf16_t*)(ws + OFF_GT_HI);
  bf16_t* Gt_lo = (bf16_t*)(ws + OFF_GT_LO);
  float*  S    = (float*)(ws + OFF_S);
  float*  veff = (float*)(ws + OFF_VEFF);
  float*  vweff = (float*)(ws + OFF_VW);
  float*  cc   = (float*)(ws + OFF_CC);
  float*  w    = (float*)(ws + OFF_WVEC);

  dim3 blk(256);
  const int M = GG * LL;  // 32768

  // preparation
  prep_qk_kernel<<<dim3(512), blk, 0, stream>>>(Wq, Wk, Wq_hi, Wq_lo, Wk_hi, Wk_lo);
  chain_kernel<<<dim3(1), blk, 0, stream>>>(Wv, W1, b1, W2, b2, W3, b3, W4, b4, vweff, cc);
  cast_split_kernel<<<dim3(M * FF / 4 / 256), blk, 0, stream>>>(info, info_hi, info_lo);
  veff_kernel<<<dim3(M / 4), blk, 0, stream>>>(info, vweff, lengths, veff);

  // Gt = Wk @ Wq^T (split) so that Gt^T = G = Wq @ Wk^T
  gemm_bt<128, true, true, 2, 0><<<dim3(4, 4, 1), blk, 0, stream>>>(
      Wk_hi, Wk_lo, 512, 0, Wq_hi, Wq_lo, 512, 0, Gt_hi, Gt_lo, 512, 0, 512, nullptr);

  // T = info @ G (split out), skip fully-masked row blocks
  gemm_bt<128, true, true, 2, 1><<<dim3(4, M / 128, 1), blk, 0, stream>>>(
      info_hi, info_lo, 512, 0, Gt_hi, Gt_lo, 512, 0, T_hi, T_lo, 512, 0, 512, lengths);

  // S[g] = T[g] @ info[g]^T (3-term split -> fp32), skip masked row/col tiles
  gemm_bt<128, true, true, 0, 3><<<dim3(2, 2, GG), blk, 0, stream>>>(
      T_hi, T_lo, 512, 256L * 512, info_hi, info_lo, 512, 256L * 512,
      S, nullptr, 256, 256L * 256, 512, lengths);

  // fused softmax + scorer -> w
  softmax_dot_kernel<<<dim3(M / 4), blk, 0, stream>>>(S, veff, cc, lengths, w);

  // out = einsum('gsl,gl->sg')
  out_kernel<<<dim3(GG, SS / 4), blk, 0, stream>>>(raw, w, lengths, out);
}